// Round 9
// baseline (472.937 us; speedup 1.0000x reference)
//
#include <hip/hip_runtime.h>

// 3D reaction-diffusion tumor solver, 160^3 f32 grid, 30 explicit Euler steps.
// R11: persistent kernel with SCOPED COHERENCE - no L2 flush/invalidate.
//
// R0-R10 post-mortem: SEVEN structurally different implementations (30
// launches, coop grid barrier, neighbor flags, LDS staging, 2-step fusion,
// occupancy 24->96%) all time 474+-5us = 15.8us/step. Shared mechanism:
// every dependent step does an agent-scope release+acquire (explicit fence,
// cg::sync, or implicit kernel boundary) = buffer_wbl2 (flush whole dirty
// L2, ~16.4MB/step -> WRITE_SIZE 487MB/dispatch to HBM) + buffer_inv
// (invalidate L2 -> ~57MB/step reads refetch from Infinity Cache). ~73MB/step
// through IC at ~5TB/s ~= 15us/step, invariant to everything we tried.
//
// R11 removes it: no agent fences in the loop. Interior data stays in the
// producing XCD's L2 (normal stores; sc0 loads bypass stale vL1 and hit L2).
// Only cross-XCD halo links use sc1 (read/write-through at the coherence
// point). Links are classified at RUNTIME from HW_REG_XCC_ID published per
// block - no assumption on block->XCD mapping (unknown mappings degrade to
// sc1, still correct). Sync = R8's proven neighbor-flag protocol with
// RELAXED agent atomics + vmcnt drains (via __syncthreads) only.
// x-neighbors via LDS from register state (-4 vmem/thr/step). Triple buffer.

#define NX 160
#define NY 160
#define NZ 160
#define NXQ (NX / 4)              // 40 float4 groups per row
#define NPLANE (NX * NY)          // 25600 floats per z-plane
#define NGROUPS (NZ * NY * NXQ)   // 1,024,000 float4 groups

// --- cooperative config: 512-thread blocks, contiguous z-pairs ---
#define CT_BS 512
#define CT_NTHREADS (NGROUPS / 2)        // 512,000
#define CT_NBLOCKS (CT_NTHREADS / CT_BS) // 1000

// --- fallback config (R2): 2 groups/thread, strided halves ---
#define FB_NTHREADS (NGROUPS / 2)      // 512,000
#define FB_NBLOCKS (FB_NTHREADS / 256) // 2000

typedef float f32x4 __attribute__((ext_vector_type(4)));

// ---- sync + buffer state (zero-init at module load) ----
__device__ unsigned int g_flag[CT_NBLOCKS * 16];  // one flag per 64B line
__device__ unsigned int g_xcdmap[CT_NBLOCKS];     // per-block physical XCC id
__device__ __align__(16) float g_mid[NGROUPS * 4]; // third grid buffer

// Scoped-load/store asm (flg = "" / " sc0" / " sc1").
#define GLD4(dst, voff, base, flg) \
    asm volatile("global_load_dwordx4 %0, %1, %2" flg \
                 : "=v"(dst) : "v"(voff), "s"(base))
#define GLD1(dst, voff, base, flg) \
    asm volatile("global_load_dword %0, %1, %2" flg \
                 : "=v"(dst) : "v"(voff), "s"(base))
#define GST4(voff, val, base, flg) \
    asm volatile("global_store_dwordx4 %0, %1, %2" flg \
                 :: "v"(voff), "v"(val), "s"(base) : "memory")

__device__ __forceinline__ f32x4 ld4v(const float* p) {
    return *reinterpret_cast<const f32x4*>(p);
}

// One Euler step for a float4 column (identical FP order to all prior rounds).
__device__ __forceinline__ f32x4 step_cell(
    f32x4 cc, f32x4 ym, f32x4 yp, f32x4 zm, f32x4 zp,
    float xl, float xr, f32x4 tm, float D, float rho, float delta_t)
{
    f32x4 o;
    float lap, g;
    lap = xl    + cc[1] + ym[0] + yp[0] + zm[0] + zp[0] - 6.f * cc[0];
    g   = D * lap + rho * cc[0] * (1.f - cc[0]) - 2.f * tm[0] * cc[0];
    o[0] = fminf(fmaxf(cc[0] + g * delta_t, 0.f), 1.f);
    lap = cc[0] + cc[2] + ym[1] + yp[1] + zm[1] + zp[1] - 6.f * cc[1];
    g   = D * lap + rho * cc[1] * (1.f - cc[1]) - 2.f * tm[1] * cc[1];
    o[1] = fminf(fmaxf(cc[1] + g * delta_t, 0.f), 1.f);
    lap = cc[1] + cc[3] + ym[2] + yp[2] + zm[2] + zp[2] - 6.f * cc[2];
    g   = D * lap + rho * cc[2] * (1.f - cc[2]) - 2.f * tm[2] * cc[2];
    o[2] = fminf(fmaxf(cc[2] + g * delta_t, 0.f), 1.f);
    lap = cc[2] + xr    + ym[3] + yp[3] + zm[3] + zp[3] - 6.f * cc[3];
    g   = D * lap + rho * cc[3] * (1.f - cc[3]) - 2.f * tm[3] * cc[3];
    o[3] = fminf(fmaxf(cc[3] + g * delta_t, 0.f), 1.f);
    return o;
}

// ---------------- scoped-coherence all-steps kernel ----------------
__global__ __launch_bounds__(CT_BS, 8) void therapy_all(
    const float* __restrict__ c_init,
    const float* __restrict__ ther,
    float* __restrict__ out,
    float* __restrict__ ws,
    const float* __restrict__ Dp,
    const float* __restrict__ rhop,
    const float* __restrict__ dtp,
    const int* __restrict__ stepsp)
{
    __shared__ float2 lx[2][CT_BS];   // per-plane {lane0(.x for xr), lane3(.y for xl)}

    // XCD swizzle: with round-robin dispatch each XCD owns 125 contiguous
    // logical blocks = a contiguous 20-plane z-slab (locality optimization
    // only - correctness comes from the runtime link classification below).
    const int lb  = (blockIdx.x & 7) * (CT_NBLOCKS / 8) + (blockIdx.x >> 3);
    const int tid = lb * CT_BS + threadIdx.x;
    const int tx  = threadIdx.x;

    const int xq = tid % NXQ;
    const int t2 = tid / NXQ;
    const int y  = t2 % NY;
    const int k  = t2 / NY;            // z-pair index, planes 2k and 2k+1

    const int   steps   = *stepsp;
    const float D       = *Dp;
    const float rho     = *rhop;
    const float delta_t = *dtp / (float)steps;

    // Monotone flag base: own flag at entry (all blocks post steps+1 flags
    // per launch -> equal at entry -> replay-safe, nothing to reset).
    const unsigned int fbase =
        __hip_atomic_load(&g_flag[lb * 16], __ATOMIC_RELAXED,
                          __HIP_MEMORY_SCOPE_AGENT);

    const int  offym = (y > 0)        ? -NX : 0;
    const int  offyp = (y < NY - 1)   ?  NX : 0;
    const int  offxl = (xq > 0)       ? -1  : 0;
    const bool mym = (y == 0), myp = (y == NY - 1);
    const bool mxl = (xq == 0), mxr = (xq == NXQ - 1);
    const bool mzm = (k == 0);
    const bool mzp = (k == NZ / 2 - 1);
    const int  offzm = mzm ? 0 : -NPLANE;
    const int  offzp = mzp ? 0 :  NPLANE;

    const int b0 = (2 * k * NY + y) * NX + xq * 4;  // plane 2k (floats)
    const int b1 = b0 + NPLANE;                     // plane 2k+1

    // Byte voffsets for saddr-form loads (plane-1 uses base+NPLANE*4).
    const unsigned o_b0 = (unsigned)b0 * 4u;
    const unsigned o_ym = (unsigned)(b0 + offym) * 4u;
    const unsigned o_yp = (unsigned)(b0 + offyp) * 4u;
    const unsigned o_xl = (unsigned)(b0 + offxl) * 4u;
    const unsigned o_xr = (unsigned)(b0 + (mxr ? 3 : 4)) * 4u;
    const unsigned o_zm = (unsigned)(b0 + offzm) * 4u;
    const unsigned o_zp = (unsigned)(b1 + offzp) * 4u;

    // Persistent register state.
    const f32x4 tv0 = ld4v(ther + b0);
    const f32x4 tv1 = ld4v(ther + b1);
    f32x4 cv0 = ld4v(c_init + b0);
    f32x4 cv1 = ld4v(c_init + b1);

    // ---- prologue: publish physical XCC id, handshake, classify links ----
    unsigned int myx;
    asm volatile("s_getreg_b32 %0, hwreg(HW_REG_XCC_ID)" : "=s"(myx));
    if (tx == 0) {
        __hip_atomic_store(&g_xcdmap[lb], myx, __ATOMIC_RELAXED,
                           __HIP_MEMORY_SCOPE_AGENT);
        asm volatile("s_waitcnt vmcnt(0)" ::: "memory");  // map at IC first
        __hip_atomic_store(&g_flag[lb * 16], fbase + 1u, __ATOMIC_RELAXED,
                           __HIP_MEMORY_SCOPE_AGENT);
    }
    if (tx < 6) {
        const int d = (tx == 0) ? -13 : (tx == 1) ? -12 : (tx == 2) ? -1
                    : (tx == 3) ?   1 : (tx == 4) ?  12 : 13;
        int nb = lb + d;
        nb = nb < 0 ? 0 : (nb >= CT_NBLOCKS ? CT_NBLOCKS - 1 : nb);
        while (__hip_atomic_load(&g_flag[nb * 16], __ATOMIC_RELAXED,
                                 __HIP_MEMORY_SCOPE_AGENT) < fbase + 1u) {
            __builtin_amdgcn_s_sleep(2);
        }
    }
    __syncthreads();

    #define MAPLD(b) __hip_atomic_load(&g_xcdmap[(b)], __ATOMIC_RELAXED, \
                                       __HIP_MEMORY_SCOPE_AGENT)
    const unsigned xm13 = (lb >= 13)             ? MAPLD(lb - 13) : myx;
    const unsigned xm12 = (lb >= 12)             ? MAPLD(lb - 12) : myx;
    const unsigned xm1  = (lb >= 1)              ? MAPLD(lb - 1)  : myx;
    const unsigned xp1  = (lb < CT_NBLOCKS - 1)  ? MAPLD(lb + 1)  : myx;
    const unsigned xp12 = (lb < CT_NBLOCKS - 12) ? MAPLD(lb + 12) : myx;
    const unsigned xp13 = (lb < CT_NBLOCKS - 13) ? MAPLD(lb + 13) : myx;

    const int zmb = (tid >= 6400) ? ((tid - 6400) >> 9) : lb;
    const int zpb = (tid + 6400 < CT_NTHREADS) ? ((tid + 6400) >> 9) : lb;
    const unsigned xzm = (zmb == lb - 13) ? xm13 : (zmb == lb - 12) ? xm12 : myx;
    const unsigned xzp = (zpb == lb + 13) ? xp13 : (zpb == lb + 12) ? xp12 : myx;

    const bool zmX = (xzm != myx);                       // zm load / n0 z-reader
    const bool zpX = (xzp != myx);                       // zp load / n1 z-reader
    const bool ymX = (tx < NXQ)         && (xm1 != myx); // y-1 producer in lb-1
    const bool ypX = (tx >= CT_BS - NXQ) && (xp1 != myx);
    const bool xlX = (tx == 0)          && (xm1 != myx);
    const bool xrX = (tx == CT_BS - 1)  && (xp1 != myx);
    const bool st0X = zmX || ymX || ypX || xlX || xrX;   // n0 has a cross reader
    const bool st1X = zpX || ymX || ypX || xlX || xrX;

    // Triple buffer; OFF aligns the cycle so step steps-1 lands in out.
    const int OFF = (3 - (steps - 1) % 3) % 3;

    const float* rd = c_init;
    for (int i = 0; i < steps; ++i) {
        const int s = (i + OFF) % 3;
        float* wr = (s == 0) ? out : (s == 1) ? ws : g_mid;

        // A: publish x-exchange values (previous-step cv == rd values)
        lx[0][tx] = make_float2(cv0[0], cv0[3]);
        lx[1][tx] = make_float2(cv1[0], cv1[3]);

        // B: wait for 6 dependency blocks to have finished step i-1
        if (i > 0 && tx < 6) {
            const int d = (tx == 0) ? -13 : (tx == 1) ? -12 : (tx == 2) ? -1
                        : (tx == 3) ?   1 : (tx == 4) ?  12 : 13;
            int nb = lb + d;
            nb = nb < 0 ? 0 : (nb >= CT_NBLOCKS ? CT_NBLOCKS - 1 : nb);
            const unsigned tgt = fbase + 1u + (unsigned)i;
            while (__hip_atomic_load(&g_flag[nb * 16], __ATOMIC_RELAXED,
                                     __HIP_MEMORY_SCOPE_AGENT) < tgt) {
                __builtin_amdgcn_s_sleep(2);
            }
        }
        __syncthreads();   // joins block; also orders LDS writes vs reads

        // C: issue neighbor loads (sc0 = own-XCD L2; sc1 = cross-XCD via IC)
        const float* rd1 = rd + NPLANE;
        f32x4 ym0, yp0, ym1, yp1, zmg, zpg;
        if (ymX) { GLD4(ym0, o_ym, rd, " sc1"); GLD4(ym1, o_ym, rd1, " sc1"); }
        else     { GLD4(ym0, o_ym, rd, " sc0"); GLD4(ym1, o_ym, rd1, " sc0"); }
        if (ypX) { GLD4(yp0, o_yp, rd, " sc1"); GLD4(yp1, o_yp, rd1, " sc1"); }
        else     { GLD4(yp0, o_yp, rd, " sc0"); GLD4(yp1, o_yp, rd1, " sc0"); }
        if (zmX) { GLD4(zmg, o_zm, rd, " sc1"); } else { GLD4(zmg, o_zm, rd, " sc0"); }
        if (zpX) { GLD4(zpg, o_zp, rd, " sc1"); } else { GLD4(zpg, o_zp, rd, " sc0"); }
        float xl0, xr0, xl1, xr1;
        if (tx == 0) {
            if (xlX) { GLD1(xl0, o_xl, rd, " sc1"); GLD1(xl1, o_xl, rd1, " sc1"); }
            else     { GLD1(xl0, o_xl, rd, " sc0"); GLD1(xl1, o_xl, rd1, " sc0"); }
        } else { xl0 = lx[0][tx - 1].y; xl1 = lx[1][tx - 1].y; }
        if (tx == CT_BS - 1) {
            if (xrX) { GLD1(xr0, o_xr, rd, " sc1"); GLD1(xr1, o_xr, rd1, " sc1"); }
            else     { GLD1(xr0, o_xr, rd, " sc0"); GLD1(xr1, o_xr, rd1, " sc0"); }
        } else { xr0 = lx[0][tx + 1].x; xr1 = lx[1][tx + 1].x; }
        asm volatile("s_waitcnt vmcnt(0)" ::: "memory");
        __builtin_amdgcn_sched_barrier(0);

        // D: boundary masks + compute (z-pair inner faces from registers)
        const f32x4 z4 = {0.f, 0.f, 0.f, 0.f};
        if (mym) { ym0 = z4; ym1 = z4; }
        if (myp) { yp0 = z4; yp1 = z4; }
        if (mzm) zmg = z4;
        if (mzp) zpg = z4;
        if (mxl) { xl0 = 0.f; xl1 = 0.f; }
        if (mxr) { xr0 = 0.f; xr1 = 0.f; }

        const f32x4 n0 = step_cell(cv0, ym0, yp0, zmg, cv1, xl0, xr0, tv0,
                                   D, rho, delta_t);
        const f32x4 n1 = step_cell(cv1, ym1, yp1, cv0, zpg, xl1, xr1, tv1,
                                   D, rho, delta_t);

        // E: stores (interior stay dirty in local L2; cross-read cells sc1)
        float* wr1 = wr + NPLANE;
        if (st0X) { GST4(o_b0, n0, wr, " sc1"); } else { GST4(o_b0, n0, wr, ""); }
        if (st1X) { GST4(o_b0, n1, wr1, " sc1"); } else { GST4(o_b0, n1, wr1, ""); }

        // F: drain this block's stores (syncthreads emits vmcnt(0) per wave
        //    before s_barrier), then post progress with a RELAXED agent store
        //    - no wbl2, no inv.
        __syncthreads();
        if (tx == 0) {
            __hip_atomic_store(&g_flag[lb * 16], fbase + 2u + (unsigned)i,
                               __ATOMIC_RELAXED, __HIP_MEMORY_SCOPE_AGENT);
        }

        cv0 = n0;
        cv1 = n1;
        rd = wr;
    }
}

// ---------------- fallback per-step kernel (R2, passed @476us) ----------------
__global__ __launch_bounds__(256) void therapy_step(
    const float* __restrict__ src,
    const float* __restrict__ ther,
    float* __restrict__ dst,
    const float* __restrict__ Dp,
    const float* __restrict__ rhop,
    const float* __restrict__ dtp,
    const int* __restrict__ stepsp)
{
    const int tid = blockIdx.x * blockDim.x + threadIdx.x;

    const int xq = tid % NXQ;
    const int t2 = tid / NXQ;
    const int y  = t2 % NY;
    const int z0 = t2 / NY;             // 0..79
    const int base0 = tid * 4;          // group 0: z in [0,80)
    const int base1 = base0 + 80 * NPLANE;  // group 1: z in [80,160)

    const int offym = (y > 0)        ? -NX : 0;
    const int offyp = (y < NY - 1)   ?  NX : 0;
    const int offxl = (xq > 0)       ? -1  : 0;
    const int offxr = (xq < NXQ - 1) ?  4  : 3;
    const int offzm0 = (z0 > 0)      ? -NPLANE : 0;
    const int offzp1 = (z0 < 79)     ?  NPLANE : 0;

    const f32x4 cc0 = ld4v(src + base0);
    const f32x4 cc1 = ld4v(src + base1);
    f32x4 ym0 = ld4v(src + base0 + offym);
    f32x4 ym1 = ld4v(src + base1 + offym);
    f32x4 yp0 = ld4v(src + base0 + offyp);
    f32x4 yp1 = ld4v(src + base1 + offyp);
    f32x4 zm0 = ld4v(src + base0 + offzm0);
    const f32x4 zm1 = ld4v(src + base1 - NPLANE);
    const f32x4 zp0 = ld4v(src + base0 + NPLANE);
    f32x4 zp1 = ld4v(src + base1 + offzp1);
    float xl0 = src[base0 + offxl];
    float xl1 = src[base1 + offxl];
    float xr0 = src[base0 + offxr];
    float xr1 = src[base1 + offxr];
    const f32x4 tm0 = ld4v(ther + base0);
    const f32x4 tm1 = ld4v(ther + base1);

    const float D       = *Dp;
    const float rho     = *rhop;
    const float delta_t = *dtp / (float)(*stepsp);

    const f32x4 z4 = {0.f, 0.f, 0.f, 0.f};
    if (y == 0)        { ym0 = z4; ym1 = z4; }
    if (y == NY - 1)   { yp0 = z4; yp1 = z4; }
    if (z0 == 0)       { zm0 = z4; }
    if (z0 == 79)      { zp1 = z4; }
    if (xq == 0)       { xl0 = 0.f; xl1 = 0.f; }
    if (xq == NXQ - 1) { xr0 = 0.f; xr1 = 0.f; }

    const f32x4 o0 = step_cell(cc0, ym0, yp0, zm0, zp0, xl0, xr0, tm0,
                               D, rho, delta_t);
    *reinterpret_cast<f32x4*>(dst + base0) = o0;
    const f32x4 o1 = step_cell(cc1, ym1, yp1, zm1, zp1, xl1, xr1, tm1,
                               D, rho, delta_t);
    *reinterpret_cast<f32x4*>(dst + base1) = o1;
}

extern "C" void kernel_launch(void* const* d_in, const int* in_sizes, int n_in,
                              void* d_out, int out_size, void* d_ws, size_t ws_size,
                              hipStream_t stream) {
    const float* c_init = (const float*)d_in[0];
    const float* Dp     = (const float*)d_in[1];
    const float* rhop   = (const float*)d_in[2];
    const float* dtp    = (const float*)d_in[3];
    const float* ther   = (const float*)d_in[4];
    const int*   stepsp = (const int*)d_in[5];

    float* out = (float*)d_out;
    float* wsA = (float*)d_ws;   // grid buffer (16.4 MB)

    // ---- gate the cooperative path (computed once) ----
    static int coop_ok = -1;
    if (coop_ok < 0) {
        coop_ok = 0;
        int dev = 0;
        if (hipGetDevice(&dev) == hipSuccess) {
            int coopAttr = 0, ncu = 0, maxb = 0;
            if (hipDeviceGetAttribute(&coopAttr, hipDeviceAttributeCooperativeLaunch, dev) == hipSuccess &&
                coopAttr != 0 &&
                hipDeviceGetAttribute(&ncu, hipDeviceAttributeMultiprocessorCount, dev) == hipSuccess &&
                hipOccupancyMaxActiveBlocksPerMultiprocessor(
                    &maxb, (const void*)therapy_all, CT_BS, 0) == hipSuccess &&
                (long)maxb * (long)ncu >= (long)CT_NBLOCKS) {
                coop_ok = 1;
            }
        }
    }

    if (coop_ok == 1) {
        void* args[] = {
            (void*)&c_init, (void*)&ther, (void*)&out, (void*)&wsA,
            (void*)&Dp, (void*)&rhop, (void*)&dtp, (void*)&stepsp
        };
        if (hipLaunchCooperativeKernel((void*)therapy_all,
                                       dim3(CT_NBLOCKS), dim3(CT_BS),
                                       args, 0, stream) == hipSuccess) {
            return;
        }
        coop_ok = 0;  // launch rejected -> permanent fallback
    }

    // ---- fallback: 30 per-step launches (proven R2 path) ----
    const dim3 block(256);
    const dim3 grid(FB_NBLOCKS);
    const float* src = c_init;
    for (int i = 0; i < 30; ++i) {
        float* dst = (i & 1) ? out : wsA;
        therapy_step<<<grid, block, 0, stream>>>(src, ther, dst, Dp, rhop, dtp, stepsp);
        src = dst;
    }
}

// Round 10
// 472.850 us; speedup vs baseline: 1.0002x; 1.0002x over previous
//
#include <hip/hip_runtime.h>

// 3D reaction-diffusion tumor solver, 160^3 f32 grid, 30 explicit Euler steps.
// R12: scoped-coherence persistent kernel at 256-THREAD BLOCKS.
//
// R11 post-mortem: the scoped-coherence kernel (no L2 flush/invalidate; sc0
// intra-XCD loads, sc1 cross-XCD halo) ran at 186us profiled = 2.5x the 475us
// plateau -> the agent-fence L2-flush theory is CONFIRMED. But timed stayed
// 473us. Audit of all rounds: timed==coop only when blocks were 256 threads
// (R4: 3431~3483, R5: 914~831); every >=320-thread round timed ~476 = the
// fallback. Mechanism: hipLaunchCooperativeKernel with >256-thread blocks is
// REJECTED during the timed harness's graph capture; the gated error check
// silently fell back. R12 re-blocks R11's kernel to 256 threads:
//   - 1000 blocks x 256 thr, each thread owns a z-QUAD (4 contiguous planes;
//     2 internal z-faces from registers; z-halo = 2 loads per 4 planes)
//   - q = lb/25 block-uniform; deps = {-25,-1,+1,+25}
//   - launch_bounds(256,4) -> <=128 VGPR, 8KB LDS -> 4 blocks/CU, 1024>=1000
//   - same runtime XCC-id link classification, relaxed agent flags, triple
//     buffer, LDS x-exchange, proven 476us fallback.

#define NX 160
#define NY 160
#define NZ 160
#define NXQ (NX / 4)              // 40 float4 groups per row
#define NPLANE (NX * NY)          // 25600 floats per z-plane
#define NGROUPS (NZ * NY * NXQ)   // 1,024,000 float4 groups

// --- cooperative config: 256-thread blocks, z-quads ---
#define CT_BS 256
#define CT_NTHREADS (NGROUPS / 4)        // 256,000 (4 planes each)
#define CT_NBLOCKS (CT_NTHREADS / CT_BS) // 1000
#define BPQ 25                           // blocks per z-quad slab (6400/256)

// --- fallback config (R2): 2 groups/thread, strided halves ---
#define FB_NTHREADS (NGROUPS / 2)      // 512,000
#define FB_NBLOCKS (FB_NTHREADS / 256) // 2000

typedef float f32x4 __attribute__((ext_vector_type(4)));

// ---- sync + buffer state (zero-init at module load) ----
__device__ unsigned int g_flag[CT_NBLOCKS * 16];   // one flag per 64B line
__device__ unsigned int g_xcdmap[CT_NBLOCKS];      // per-block physical XCC id
__device__ __align__(16) float g_mid[NGROUPS * 4]; // third grid buffer

// Scoped-load/store asm (flg = "" / " sc0" / " sc1").
#define GLD4(dst, voff, base, flg) \
    asm volatile("global_load_dwordx4 %0, %1, %2" flg \
                 : "=v"(dst) : "v"(voff), "s"(base))
#define GLD1(dst, voff, base, flg) \
    asm volatile("global_load_dword %0, %1, %2" flg \
                 : "=v"(dst) : "v"(voff), "s"(base))
#define GST4(voff, val, base, flg) \
    asm volatile("global_store_dwordx4 %0, %1, %2" flg \
                 :: "v"(voff), "v"(val), "s"(base) : "memory")

__device__ __forceinline__ f32x4 ld4v(const float* p) {
    return *reinterpret_cast<const f32x4*>(p);
}

// One Euler step for a float4 column (identical FP order to all prior rounds).
__device__ __forceinline__ f32x4 step_cell(
    f32x4 cc, f32x4 ym, f32x4 yp, f32x4 zm, f32x4 zp,
    float xl, float xr, f32x4 tm, float D, float rho, float delta_t)
{
    f32x4 o;
    float lap, g;
    lap = xl    + cc[1] + ym[0] + yp[0] + zm[0] + zp[0] - 6.f * cc[0];
    g   = D * lap + rho * cc[0] * (1.f - cc[0]) - 2.f * tm[0] * cc[0];
    o[0] = fminf(fmaxf(cc[0] + g * delta_t, 0.f), 1.f);
    lap = cc[0] + cc[2] + ym[1] + yp[1] + zm[1] + zp[1] - 6.f * cc[1];
    g   = D * lap + rho * cc[1] * (1.f - cc[1]) - 2.f * tm[1] * cc[1];
    o[1] = fminf(fmaxf(cc[1] + g * delta_t, 0.f), 1.f);
    lap = cc[1] + cc[3] + ym[2] + yp[2] + zm[2] + zp[2] - 6.f * cc[2];
    g   = D * lap + rho * cc[2] * (1.f - cc[2]) - 2.f * tm[2] * cc[2];
    o[2] = fminf(fmaxf(cc[2] + g * delta_t, 0.f), 1.f);
    lap = cc[2] + xr    + ym[3] + yp[3] + zm[3] + zp[3] - 6.f * cc[3];
    g   = D * lap + rho * cc[3] * (1.f - cc[3]) - 2.f * tm[3] * cc[3];
    o[3] = fminf(fmaxf(cc[3] + g * delta_t, 0.f), 1.f);
    return o;
}

// ---------------- scoped-coherence all-steps kernel ----------------
__global__ __launch_bounds__(CT_BS, 4) void therapy_all(
    const float* __restrict__ c_init,
    const float* __restrict__ ther,
    float* __restrict__ out,
    float* __restrict__ ws,
    const float* __restrict__ Dp,
    const float* __restrict__ rhop,
    const float* __restrict__ dtp,
    const int* __restrict__ stepsp)
{
    __shared__ float2 lx[4][CT_BS];   // per-plane {x0 (reader's xr), x3 (xl)}

    // Bijective XCD swizzle (1000 % 8 == 0): each XCD owns 125 contiguous
    // logical blocks = 5 whole z-quad slabs.
    const int lb = (blockIdx.x & 7) * (CT_NBLOCKS / 8) + (blockIdx.x >> 3);
    const int tx = threadIdx.x;
    const int tid = lb * CT_BS + tx;

    const int xq = tid % NXQ;           // 0..39
    const int t2 = tid / NXQ;
    const int y  = t2 % NY;             // 0..159
    const int q  = lb / BPQ;            // z-quad index, block-uniform (0..39)

    const int   steps   = *stepsp;
    const float D       = *Dp;
    const float rho     = *rhop;
    const float delta_t = *dtp / (float)steps;

    const unsigned int fbase =
        __hip_atomic_load(&g_flag[lb * 16], __ATOMIC_RELAXED,
                          __HIP_MEMORY_SCOPE_AGENT);

    const int  offym = (y > 0)        ? -NX : 0;
    const int  offyp = (y < NY - 1)   ?  NX : 0;
    const int  offxl = (xq > 0)       ? -1  : 0;
    const bool mym = (y == 0), myp = (y == NY - 1);
    const bool mxl = (xq == 0), mxr = (xq == NXQ - 1);
    const bool mzm = (q == 0);
    const bool mzp = (q == 39);

    const int b0 = ((4 * q) * NY + y) * NX + 4 * xq;   // plane 4q (floats)
    const int b3 = b0 + 3 * NPLANE;                    // plane 4q+3

    const unsigned o_c  = (unsigned)b0 * 4u;
    const unsigned o_ym = (unsigned)(b0 + offym) * 4u;
    const unsigned o_yp = (unsigned)(b0 + offyp) * 4u;
    const unsigned o_xl = (unsigned)(b0 + offxl) * 4u;
    const unsigned o_xr = (unsigned)(b0 + (mxr ? 3 : 4)) * 4u;
    const unsigned o_zm = (unsigned)(b0 + (mzm ? 0 : -NPLANE)) * 4u;
    const unsigned o_zp = (unsigned)(b3 + (mzp ? 0 :  NPLANE)) * 4u;

    f32x4 tv[4], cv[4];
#pragma unroll
    for (int p = 0; p < 4; ++p) {
        tv[p] = ld4v(ther   + b0 + p * NPLANE);
        cv[p] = ld4v(c_init + b0 + p * NPLANE);
    }

    // ---- prologue: publish physical XCC id, handshake, classify links ----
    unsigned int myx;
    asm volatile("s_getreg_b32 %0, hwreg(HW_REG_XCC_ID)" : "=s"(myx));
    if (tx == 0) {
        __hip_atomic_store(&g_xcdmap[lb], myx, __ATOMIC_RELAXED,
                           __HIP_MEMORY_SCOPE_AGENT);
        asm volatile("s_waitcnt vmcnt(0)" ::: "memory");
        __hip_atomic_store(&g_flag[lb * 16], fbase + 1u, __ATOMIC_RELAXED,
                           __HIP_MEMORY_SCOPE_AGENT);
    }
    if (tx < 4) {
        const int d = (tx == 0) ? -BPQ : (tx == 1) ? -1 : (tx == 2) ? 1 : BPQ;
        int nb = lb + d;
        nb = nb < 0 ? 0 : (nb >= CT_NBLOCKS ? CT_NBLOCKS - 1 : nb);
        while (__hip_atomic_load(&g_flag[nb * 16], __ATOMIC_RELAXED,
                                 __HIP_MEMORY_SCOPE_AGENT) < fbase + 1u) {
            __builtin_amdgcn_s_sleep(2);
        }
    }
    __syncthreads();

    #define MAPLD(b) __hip_atomic_load(&g_xcdmap[(b)], __ATOMIC_RELAXED, \
                                       __HIP_MEMORY_SCOPE_AGENT)
    const unsigned xm25 = (lb >= BPQ)              ? MAPLD(lb - BPQ) : myx;
    const unsigned xm1  = (lb >= 1)                ? MAPLD(lb - 1)   : myx;
    const unsigned xp1  = (lb < CT_NBLOCKS - 1)    ? MAPLD(lb + 1)   : myx;
    const unsigned xp25 = (lb < CT_NBLOCKS - BPQ)  ? MAPLD(lb + BPQ) : myx;

    const bool zmX = (xm25 != myx);
    const bool zpX = (xp25 != myx);
    const bool ymX = (tx < NXQ)          && (xm1 != myx);
    const bool ypX = (tx >= CT_BS - NXQ) && (xp1 != myx);
    const bool xlX = (tx == 0)           && (xm1 != myx);
    const bool xrX = (tx == CT_BS - 1)   && (xp1 != myx);
    const bool stYX = (tx < NXQ && xm1 != myx) ||
                      (tx >= CT_BS - NXQ && xp1 != myx);
    const bool st0X = stYX || zmX;
    const bool st3X = stYX || zpX;

    const int OFF = (3 - (steps - 1) % 3) % 3;

    const float* rd = c_init;
    for (int i = 0; i < steps; ++i) {
        const int s = (i + OFF) % 3;
        float* wr = (s == 0) ? out : (s == 1) ? ws : g_mid;

        // A: publish x-exchange values (previous-step cv == rd values)
#pragma unroll
        for (int p = 0; p < 4; ++p)
            lx[p][tx] = make_float2(cv[p][0], cv[p][3]);

        // B: wait for the 4 dependency blocks to have finished step i-1
        if (i > 0 && tx < 4) {
            const int d = (tx == 0) ? -BPQ : (tx == 1) ? -1
                        : (tx == 2) ?    1 : BPQ;
            int nb = lb + d;
            nb = nb < 0 ? 0 : (nb >= CT_NBLOCKS ? CT_NBLOCKS - 1 : nb);
            const unsigned tgt = fbase + 1u + (unsigned)i;
            while (__hip_atomic_load(&g_flag[nb * 16], __ATOMIC_RELAXED,
                                     __HIP_MEMORY_SCOPE_AGENT) < tgt) {
                __builtin_amdgcn_s_sleep(2);
            }
        }
        __syncthreads();

        // C: neighbor loads (sc0 = own-XCD L2; sc1 = cross-XCD via IC)
        f32x4 ym[4], yp[4], zmg, zpg;
#pragma unroll
        for (int p = 0; p < 4; ++p) {
            const unsigned po = (unsigned)(p * NPLANE * 4);
            if (ymX) { GLD4(ym[p], o_ym + po, rd, " sc1"); }
            else     { GLD4(ym[p], o_ym + po, rd, " sc0"); }
            if (ypX) { GLD4(yp[p], o_yp + po, rd, " sc1"); }
            else     { GLD4(yp[p], o_yp + po, rd, " sc0"); }
        }
        if (zmX) { GLD4(zmg, o_zm, rd, " sc1"); } else { GLD4(zmg, o_zm, rd, " sc0"); }
        if (zpX) { GLD4(zpg, o_zp, rd, " sc1"); } else { GLD4(zpg, o_zp, rd, " sc0"); }
        float xl[4], xr[4];
        if (tx == 0) {
#pragma unroll
            for (int p = 0; p < 4; ++p) {
                const unsigned po = (unsigned)(p * NPLANE * 4);
                if (xlX) { GLD1(xl[p], o_xl + po, rd, " sc1"); }
                else     { GLD1(xl[p], o_xl + po, rd, " sc0"); }
            }
        } else {
#pragma unroll
            for (int p = 0; p < 4; ++p) xl[p] = lx[p][tx - 1].y;
        }
        if (tx == CT_BS - 1) {
#pragma unroll
            for (int p = 0; p < 4; ++p) {
                const unsigned po = (unsigned)(p * NPLANE * 4);
                if (xrX) { GLD1(xr[p], o_xr + po, rd, " sc1"); }
                else     { GLD1(xr[p], o_xr + po, rd, " sc0"); }
            }
        } else {
#pragma unroll
            for (int p = 0; p < 4; ++p) xr[p] = lx[p][tx + 1].x;
        }
        asm volatile("s_waitcnt vmcnt(0)" ::: "memory");
        __builtin_amdgcn_sched_barrier(0);

        // D: boundary masks + compute (internal z-faces from registers)
        const f32x4 z4 = {0.f, 0.f, 0.f, 0.f};
        if (mym) {
#pragma unroll
            for (int p = 0; p < 4; ++p) ym[p] = z4;
        }
        if (myp) {
#pragma unroll
            for (int p = 0; p < 4; ++p) yp[p] = z4;
        }
        if (mzm) zmg = z4;
        if (mzp) zpg = z4;
        if (mxl) {
#pragma unroll
            for (int p = 0; p < 4; ++p) xl[p] = 0.f;
        }
        if (mxr) {
#pragma unroll
            for (int p = 0; p < 4; ++p) xr[p] = 0.f;
        }

        f32x4 n[4];
        n[0] = step_cell(cv[0], ym[0], yp[0], zmg,   cv[1], xl[0], xr[0], tv[0], D, rho, delta_t);
        n[1] = step_cell(cv[1], ym[1], yp[1], cv[0], cv[2], xl[1], xr[1], tv[1], D, rho, delta_t);
        n[2] = step_cell(cv[2], ym[2], yp[2], cv[1], cv[3], xl[2], xr[2], tv[2], D, rho, delta_t);
        n[3] = step_cell(cv[3], ym[3], yp[3], cv[2], zpg,   xl[3], xr[3], tv[3], D, rho, delta_t);

        // E: stores (interior stay dirty in local L2; cross-read cells sc1)
        if (st0X) { GST4(o_c, n[0], wr, " sc1"); } else { GST4(o_c, n[0], wr, ""); }
        if (stYX) { GST4(o_c + 102400u, n[1], wr, " sc1"); }
        else      { GST4(o_c + 102400u, n[1], wr, ""); }
        if (stYX) { GST4(o_c + 204800u, n[2], wr, " sc1"); }
        else      { GST4(o_c + 204800u, n[2], wr, ""); }
        if (st3X) { GST4(o_c + 307200u, n[3], wr, " sc1"); }
        else      { GST4(o_c + 307200u, n[3], wr, ""); }

        // F: drain stores, then post progress (relaxed agent store)
        __syncthreads();
        if (tx == 0) {
            __hip_atomic_store(&g_flag[lb * 16], fbase + 2u + (unsigned)i,
                               __ATOMIC_RELAXED, __HIP_MEMORY_SCOPE_AGENT);
        }

#pragma unroll
        for (int p = 0; p < 4; ++p) cv[p] = n[p];
        rd = wr;
    }
}

// ---------------- fallback per-step kernel (R2, passed @476us) ----------------
__global__ __launch_bounds__(256) void therapy_step(
    const float* __restrict__ src,
    const float* __restrict__ ther,
    float* __restrict__ dst,
    const float* __restrict__ Dp,
    const float* __restrict__ rhop,
    const float* __restrict__ dtp,
    const int* __restrict__ stepsp)
{
    const int tid = blockIdx.x * blockDim.x + threadIdx.x;

    const int xq = tid % NXQ;
    const int t2 = tid / NXQ;
    const int y  = t2 % NY;
    const int z0 = t2 / NY;             // 0..79
    const int base0 = tid * 4;          // group 0: z in [0,80)
    const int base1 = base0 + 80 * NPLANE;  // group 1: z in [80,160)

    const int offym = (y > 0)        ? -NX : 0;
    const int offyp = (y < NY - 1)   ?  NX : 0;
    const int offxl = (xq > 0)       ? -1  : 0;
    const int offxr = (xq < NXQ - 1) ?  4  : 3;
    const int offzm0 = (z0 > 0)      ? -NPLANE : 0;
    const int offzp1 = (z0 < 79)     ?  NPLANE : 0;

    const f32x4 cc0 = ld4v(src + base0);
    const f32x4 cc1 = ld4v(src + base1);
    f32x4 ym0 = ld4v(src + base0 + offym);
    f32x4 ym1 = ld4v(src + base1 + offym);
    f32x4 yp0 = ld4v(src + base0 + offyp);
    f32x4 yp1 = ld4v(src + base1 + offyp);
    f32x4 zm0 = ld4v(src + base0 + offzm0);
    const f32x4 zm1 = ld4v(src + base1 - NPLANE);
    const f32x4 zp0 = ld4v(src + base0 + NPLANE);
    f32x4 zp1 = ld4v(src + base1 + offzp1);
    float xl0 = src[base0 + offxl];
    float xl1 = src[base1 + offxl];
    float xr0 = src[base0 + offxr];
    float xr1 = src[base1 + offxr];
    const f32x4 tm0 = ld4v(ther + base0);
    const f32x4 tm1 = ld4v(ther + base1);

    const float D       = *Dp;
    const float rho     = *rhop;
    const float delta_t = *dtp / (float)(*stepsp);

    const f32x4 z4 = {0.f, 0.f, 0.f, 0.f};
    if (y == 0)        { ym0 = z4; ym1 = z4; }
    if (y == NY - 1)   { yp0 = z4; yp1 = z4; }
    if (z0 == 0)       { zm0 = z4; }
    if (z0 == 79)      { zp1 = z4; }
    if (xq == 0)       { xl0 = 0.f; xl1 = 0.f; }
    if (xq == NXQ - 1) { xr0 = 0.f; xr1 = 0.f; }

    const f32x4 o0 = step_cell(cc0, ym0, yp0, zm0, zp0, xl0, xr0, tm0,
                               D, rho, delta_t);
    *reinterpret_cast<f32x4*>(dst + base0) = o0;
    const f32x4 o1 = step_cell(cc1, ym1, yp1, zm1, zp1, xl1, xr1, tm1,
                               D, rho, delta_t);
    *reinterpret_cast<f32x4*>(dst + base1) = o1;
}

extern "C" void kernel_launch(void* const* d_in, const int* in_sizes, int n_in,
                              void* d_out, int out_size, void* d_ws, size_t ws_size,
                              hipStream_t stream) {
    const float* c_init = (const float*)d_in[0];
    const float* Dp     = (const float*)d_in[1];
    const float* rhop   = (const float*)d_in[2];
    const float* dtp    = (const float*)d_in[3];
    const float* ther   = (const float*)d_in[4];
    const int*   stepsp = (const int*)d_in[5];

    float* out = (float*)d_out;
    float* wsA = (float*)d_ws;   // grid buffer (16.4 MB)

    // ---- gate the cooperative path (computed once) ----
    static int coop_ok = -1;
    if (coop_ok < 0) {
        coop_ok = 0;
        int dev = 0;
        if (hipGetDevice(&dev) == hipSuccess) {
            int coopAttr = 0, ncu = 0, maxb = 0;
            if (hipDeviceGetAttribute(&coopAttr, hipDeviceAttributeCooperativeLaunch, dev) == hipSuccess &&
                coopAttr != 0 &&
                hipDeviceGetAttribute(&ncu, hipDeviceAttributeMultiprocessorCount, dev) == hipSuccess &&
                hipOccupancyMaxActiveBlocksPerMultiprocessor(
                    &maxb, (const void*)therapy_all, CT_BS, 0) == hipSuccess &&
                (long)maxb * (long)ncu >= (long)CT_NBLOCKS) {
                coop_ok = 1;
            }
        }
    }

    if (coop_ok == 1) {
        void* args[] = {
            (void*)&c_init, (void*)&ther, (void*)&out, (void*)&wsA,
            (void*)&Dp, (void*)&rhop, (void*)&dtp, (void*)&stepsp
        };
        if (hipLaunchCooperativeKernel((void*)therapy_all,
                                       dim3(CT_NBLOCKS), dim3(CT_BS),
                                       args, 0, stream) == hipSuccess) {
            return;
        }
        coop_ok = 0;  // launch rejected -> permanent fallback
    }

    // ---- fallback: 30 per-step launches (proven R2 path) ----
    const dim3 block(256);
    const dim3 grid(FB_NBLOCKS);
    const float* src = c_init;
    for (int i = 0; i < 30; ++i) {
        float* dst = (i & 1) ? out : wsA;
        therapy_step<<<grid, block, 0, stream>>>(src, ther, dst, Dp, rhop, dtp, stepsp);
        src = dst;
    }
}